// Round 1
// baseline (276.360 us; speedup 1.0000x reference)
//
#include <hip/hip_runtime.h>
#include <math.h>

// Problem constants
#define B_N   4
#define CIN   21
#define HIDC  48
#define H0    81
#define NP    6561      // 81*81
#define HH    324
#define NPH   104976    // 324*324

__device__ __forceinline__ float tanh_fast(float x) {
    float e = __expf(2.f * x);
    return 1.f - 2.f / (e + 1.f);
}

// ---------------------------------------------------------------------------
// K1 v6 (unchanged): conv1 both heads (21 -> 96 = 48 o + 48 g), relu.
// MLP-first layout: block = 256 consecutive pixels, blockIdx.y = 12-oc group.
// ---------------------------------------------------------------------------
__global__ __launch_bounds__(256) void k1_conv1(
    const float* __restrict__ x,
    const float* __restrict__ w1o, const float* __restrict__ b1o,
    const float* __restrict__ w1g, const float* __restrict__ b1g,
    float* __restrict__ hid_o, float* __restrict__ hid_g)
{
    __shared__ __align__(16) float wt[189 * 12];  // [ict*12 + oc]
    __shared__ float bs[12];
    const int tid = threadIdx.x;
    const int grp = blockIdx.y;          // 0..7 ; 0..3 -> head_o, 4..7 -> head_g
    const int b   = blockIdx.z;
    const bool head_o = (grp < 4);
    const int ocb = (grp & 3) * 12;      // oc base within the head
    const float* wsrc = head_o ? w1o : w1g;
    for (int i = tid; i < 189 * 12; i += 256) {
        const int ict = i / 12, oc = i - ict * 12;
        wt[i] = wsrc[(ocb + oc) * 189 + ict];
    }
    if (tid < 12) bs[tid] = (head_o ? b1o : b1g)[ocb + tid];
    __syncthreads();

    const int px = blockIdx.x * 256 + tid;
    const bool valid = (px < NP);
    const int oy = px / H0, ox = px - oy * H0;
    const float* xb = x + (size_t)b * CIN * NP;

    float acc[12];
    #pragma unroll
    for (int j = 0; j < 12; j++) acc[j] = bs[j];

    for (int ic = 0; ic < CIN; ic++) {
        const float* xc = xb + ic * NP;
        float xv[9];
        #pragma unroll
        for (int ky = 0; ky < 3; ky++) {
            const int iy = oy + ky - 1;
            const bool rok = valid && ((unsigned)iy < (unsigned)H0);
            #pragma unroll
            for (int kx = 0; kx < 3; kx++) {
                const int ix = ox + kx - 1;
                const bool ok = rok && ((unsigned)ix < (unsigned)H0);
                xv[ky * 3 + kx] = ok ? xc[iy * H0 + ix] : 0.f;
            }
        }
        #pragma unroll
        for (int tap = 0; tap < 9; tap++) {
            const float4 w0 = *(const float4*)&wt[(ic * 9 + tap) * 12];
            const float4 w1 = *(const float4*)&wt[(ic * 9 + tap) * 12 + 4];
            const float4 w2 = *(const float4*)&wt[(ic * 9 + tap) * 12 + 8];
            const float wj[12] = {w0.x, w0.y, w0.z, w0.w, w1.x, w1.y, w1.z, w1.w,
                                  w2.x, w2.y, w2.z, w2.w};
            const float xvt = xv[tap];
            #pragma unroll
            for (int j = 0; j < 12; j++) acc[j] = fmaf(xvt, wj[j], acc[j]);
        }
    }

    if (valid) {
        float* outp = (head_o ? hid_o : hid_g) + ((size_t)b * HIDC + ocb) * NP + px;
        #pragma unroll
        for (int j = 0; j < 12; j++) outp[j * NP] = fmaxf(acc[j], 0.f);
    }
}

// ---------------------------------------------------------------------------
// K24: fused conv2 + masks + hi-res blend. Block = (low-res row h0r, half-row,
// b): 648 blocks x 256 threads, ~47.6 KB LDS (3 blocks/CU).
//   P0: stage conv2 weights + 3 reflected x rows (all 21 channels).
//   P1: conv2 partials, 6 ic-groups x 41 px, coalesced hid reads -> red LDS.
//   P2: mask epilogue (41 threads): tanh/sigmoid/softmax/hp-norm -> ml/mh/g
//       in LDS, v written straight to global. No mask round-trip to HBM.
//   PA/PB: identical to former k4 (per-(c,wq) aggregates, then 4 hi-res rows
//       x 22 planes of float4 coalesced emits), masks read from LDS.
// Eliminates k2's launch+drain, its 87.5%-idle epilogue, and the
// m_lp/m_hp/g_buf workspace traffic.
// ---------------------------------------------------------------------------
__global__ __launch_bounds__(256) void k24_conv2_up(
    const float* __restrict__ x,
    const float* __restrict__ hid_o, const float* __restrict__ hid_g,
    const float* __restrict__ w2o, const float* __restrict__ b2o,
    const float* __restrict__ w2g, const float* __restrict__ b2g,
    const float* __restrict__ beta,
    float* __restrict__ v_out, float* __restrict__ y_out,
    float* __restrict__ gup_out)
{
    __shared__ __align__(16) float wo_s[HIDC * 9 * 8];  // [(ic*9+tap)*8 + d] 13824B
    __shared__ float wg_s[HIDC * 9];                    // 1728B
    __shared__ float xrow[3][CIN][84];                  // 21168B
    __shared__ float red_u[6 * 41 * 9];                 // 8856B (aliased alp/ahp later)
    __shared__ float ml_s[9][41];
    __shared__ float mh_s[9][41];
    __shared__ float g_s[41];

    const int tid  = threadIdx.x;
    const int h0r  = blockIdx.x;         // 0..80
    const int half = blockIdx.y;         // 0..1
    const int b    = blockIdx.z;
    const int wq0  = half * 41;          // column base; half 1 covers 40 cols

    // ---- P0: stage weights + x rows -------------------------------------
    for (int i = tid; i < HIDC * 9 * 8; i += 256) {
        const int d = i / (HIDC * 9), r = i - d * (HIDC * 9);
        wo_s[r * 8 + d] = w2o[i];
    }
    for (int i = tid; i < HIDC * 9; i += 256) wg_s[i] = w2g[i];

    const int r0 = (h0r == 0) ? 1 : h0r - 1;
    const int r2 = (h0r == H0 - 1) ? H0 - 2 : h0r + 1;
    const int rr[3] = {r0, h0r, r2};
    for (int i = tid; i < 3 * CIN * H0; i += 256) {
        const int t3 = i / (CIN * H0), rem = i - t3 * CIN * H0;
        const int cc = rem / H0, wq = rem - cc * H0;
        xrow[t3][cc][wq] = x[((size_t)b * CIN + cc) * NP + rr[t3] * H0 + wq];
    }
    __syncthreads();

    // ---- P1: conv2 partial sums -----------------------------------------
    {
        const int grp = tid / 41;            // ic group 0..5 (8 ic each)
        const int pxl = tid - grp * 41;
        const int wq  = wq0 + pxl;
        const bool cactive = (grp < 6) && (wq < H0);
        if (cactive) {
            const int ic0 = grp * 8;
            const float* po = hid_o + ((size_t)b * HIDC + ic0) * NP;
            const float* pg = hid_g + ((size_t)b * HIDC + ic0) * NP;
            float a[8] = {0.f, 0.f, 0.f, 0.f, 0.f, 0.f, 0.f, 0.f};
            float ag = 0.f;
            #pragma unroll
            for (int ky = 0; ky < 3; ky++) {
                const int iy = h0r + ky - 1;
                const bool rok = ((unsigned)iy < (unsigned)H0);
                #pragma unroll
                for (int kx = 0; kx < 3; kx++) {
                    const int ix = wq + kx - 1;
                    const bool ok = rok && ((unsigned)ix < (unsigned)H0);
                    const int off = iy * H0 + ix;
                    const int tap = ky * 3 + kx;
                    #pragma unroll
                    for (int j = 0; j < 8; j++) {
                        const float vo = ok ? po[j * NP + off] : 0.f;
                        const float vg = ok ? pg[j * NP + off] : 0.f;
                        const int wb = ((ic0 + j) * 9 + tap) * 8;
                        const float4 wA = *(const float4*)&wo_s[wb];
                        const float4 wB = *(const float4*)&wo_s[wb + 4];
                        a[0] = fmaf(vo, wA.x, a[0]); a[1] = fmaf(vo, wA.y, a[1]);
                        a[2] = fmaf(vo, wA.z, a[2]); a[3] = fmaf(vo, wA.w, a[3]);
                        a[4] = fmaf(vo, wB.x, a[4]); a[5] = fmaf(vo, wB.y, a[5]);
                        a[6] = fmaf(vo, wB.z, a[6]); a[7] = fmaf(vo, wB.w, a[7]);
                        ag = fmaf(vg, wg_s[(ic0 + j) * 9 + tap], ag);
                    }
                }
            }
            float* rp = &red_u[(grp * 41 + pxl) * 9];
            #pragma unroll
            for (int n = 0; n < 8; n++) rp[n] = a[n];
            rp[8] = ag;
        }
    }
    __syncthreads();

    // ---- P2: mask epilogue (one thread per pixel of the half-row) -------
    if (tid < 41 && (wq0 + tid) < H0) {
        const int wq = wq0 + tid;
        float s[9];
        #pragma unroll
        for (int n = 0; n < 9; n++) {
            float t = 0.f;
            #pragma unroll
            for (int g = 0; g < 6; g++) t += red_u[(g * 41 + tid) * 9 + n];
            s[n] = t;
        }
        float v[8];
        #pragma unroll
        for (int n = 0; n < 8; n++) v[n] = tanh_fast(s[n] + b2o[n]);
        const float g = 1.f / (1.f + __expf(-(s[8] + b2g[0])));

        constexpr float DT[8][9] = {
            {-1, 0, 1, -1, 0, 1, -1, 0, 1},
            {-1,-1, 0, -1, 0, 1,  0, 1, 1},
            {-1,-1,-1,  0, 0, 0,  1, 1, 1},
            { 0,-1,-1,  1, 0,-1,  1, 1, 0},
            { 1, 0,-1,  1, 0,-1,  1, 0,-1},
            { 1, 1, 0,  1, 0,-1,  0,-1,-1},
            { 1, 1, 1,  0, 0, 0, -1,-1,-1},
            { 0, 1, 1, -1, 0, 1, -1,-1, 0}};
        float ker[9];
        #pragma unroll
        for (int n = 0; n < 9; n++) {
            float t = 0.f;
            #pragma unroll
            for (int d = 0; d < 8; d++) t += v[d] * DT[d][n];
            ker[n] = -0.125f * t;
        }
        ker[4] += 2.5f;
        float mx = ker[0];
        #pragma unroll
        for (int n = 1; n < 9; n++) mx = fmaxf(mx, ker[n]);
        float exn[9], sum = 0.f;
        #pragma unroll
        for (int n = 0; n < 9; n++) { exn[n] = __expf((ker[n] - mx) * 2.0f); sum += exn[n]; }
        const float rs = 1.f / sum;
        float mean = 0.f;
        #pragma unroll
        for (int n = 0; n < 9; n++) mean += ker[n];
        mean *= (1.f / 9.f);
        float den = 1e-8f;
        #pragma unroll
        for (int n = 0; n < 9; n++) den += fabsf(ker[n] - mean);
        const float rd = 1.f / den;

        #pragma unroll
        for (int n = 0; n < 9; n++) {
            ml_s[n][tid] = exn[n] * rs;
            mh_s[n][tid] = (ker[n] - mean) * rd;
        }
        g_s[tid] = g;
        // v output goes straight to global (no round-trip)
        #pragma unroll
        for (int n = 0; n < 8; n++)
            v_out[((size_t)b * 8 + n) * NP + h0r * H0 + wq] = v[n];
    }
    __syncthreads();

    // ---- PA: per-(c,wq) low-res aggregates (alp/ahp alias the red buffer)
    float* alp_s = red_u;             // [cc*41 + pxl], 861 floats
    float* ahp_s = red_u + CIN * 41;  // 861 floats (fits in 2214)
    for (int i = tid; i < CIN * 41; i += 256) {
        const int cc = i / 41, pxl = i - cc * 41;
        const int wq = wq0 + pxl;
        if (wq >= H0) continue;
        const int xm = (wq == 0) ? 1 : wq - 1;
        const int xp = (wq == H0 - 1) ? H0 - 2 : wq + 1;
        float alp = 0.f, ahp = 0.f;
        #pragma unroll
        for (int t3 = 0; t3 < 3; t3++) {
            const float p0 = xrow[t3][cc][xm];
            const float p1 = xrow[t3][cc][wq];
            const float p2 = xrow[t3][cc][xp];
            alp += p0 * ml_s[t3 * 3 + 0][pxl] + p1 * ml_s[t3 * 3 + 1][pxl] + p2 * ml_s[t3 * 3 + 2][pxl];
            ahp += p0 * mh_s[t3 * 3 + 0][pxl] + p1 * mh_s[t3 * 3 + 1][pxl] + p2 * mh_s[t3 * 3 + 2][pxl];
        }
        alp_s[cc * 41 + pxl] = alp;
        ahp_s[cc * 41 + pxl] = ahp;
    }
    __syncthreads();

    // ---- PB: emit 22 planes x 4 hi-res rows x 41 float4s ----------------
    const float tb = tanh_fast(beta[0]);
    for (int i = tid; i < 22 * 4 * 41; i += 256) {
        const int pl = i / 164, rem = i - pl * 164;
        const int dh = rem / 41, pxl = rem - dh * 41;
        const int wq = wq0 + pxl;
        if (wq >= H0) continue;
        const int H = h0r * 4 + dh;
        if (pl == 21) {
            const float g = g_s[pxl];
            *reinterpret_cast<float4*>(gup_out + (size_t)b * NPH + H * HH + wq * 4) =
                make_float4(g, g, g, g);
            continue;
        }
        const int cc = pl;
        const float g = g_s[pxl];
        const float lam = 0.15f * (1.f - g);
        const float gh = tb * g;
        const float alp = alp_s[cc * 41 + pxl];
        const float ahp = ahp_s[cc * 41 + pxl];
        // bilinear from staged rows
        const float ysf = (float)H * (80.f / 323.f);
        int y0 = (int)ysf;
        if (y0 > H0 - 2) y0 = H0 - 2;
        const float wy = ysf - (float)y0;
        const int sy = y0 - h0r + 1;    // 0 or 1 (proved in range)
        const int xm = (wq == 0) ? 1 : wq - 1;
        const int xp = (wq == H0 - 1) ? H0 - 2 : wq + 1;
        const float a0 = xrow[sy][cc][(wq == 0) ? 0 : xm];
        const float a1 = xrow[sy][cc][wq];
        const float a2 = xrow[sy][cc][(wq == H0 - 1) ? H0 - 1 : xp];
        const float b0 = xrow[sy + 1][cc][(wq == 0) ? 0 : xm];
        const float b1 = xrow[sy + 1][cc][wq];
        const float b2 = xrow[sy + 1][cc][(wq == H0 - 1) ? H0 - 1 : xp];
        float res[4];
        #pragma unroll
        for (int k = 0; k < 4; k++) {
            const int W = wq * 4 + k;
            const float xsf = (float)W * (80.f / 323.f);
            int x0 = (int)xsf;
            if (x0 > H0 - 2) x0 = H0 - 2;
            const float wx = xsf - (float)x0;
            const int sx = x0 - wq + 1;   // 0 or 1
            const float top = (sx == 0) ? a0 + (a1 - a0) * wx : a1 + (a2 - a1) * wx;
            const float bot = (sx == 0) ? b0 + (b1 - b0) * wx : b1 + (b2 - b1) * wx;
            const float xup = top + (bot - top) * wy;
            res[k] = xup + lam * (alp - xup) + gh * ahp;
        }
        *reinterpret_cast<float4*>(y_out + ((size_t)b * CIN + cc) * NPH + H * HH + wq * 4) =
            make_float4(res[0], res[1], res[2], res[3]);
    }
}

// ---------------------------------------------------------------------------
extern "C" void kernel_launch(void* const* d_in, const int* in_sizes, int n_in,
                              void* d_out, int out_size, void* d_ws, size_t ws_size,
                              hipStream_t stream)
{
    const float* x    = (const float*)d_in[0];
    const float* w1o  = (const float*)d_in[1];
    const float* b1o  = (const float*)d_in[2];
    const float* w2o  = (const float*)d_in[3];
    const float* b2o  = (const float*)d_in[4];
    const float* w1g  = (const float*)d_in[5];
    const float* b1g  = (const float*)d_in[6];
    const float* w2g  = (const float*)d_in[7];
    const float* b2g  = (const float*)d_in[8];
    const float* beta = (const float*)d_in[9];
    float* out = (float*)d_out;
    float* wsf = (float*)d_ws;

    float* hid_o = wsf;
    float* hid_g = hid_o + (size_t)B_N * HIDC * NP;

    // output layout: y [4,21,324,324], v [4,8,81,81], g_up [4,1,324,324]
    float* y_out = out;
    float* v_out = out + (size_t)B_N * CIN * NPH;
    float* gup   = v_out + (size_t)B_N * 8 * NP;

    k1_conv1<<<dim3((NP + 255) / 256, 8, B_N), 256, 0, stream>>>(
        x, w1o, b1o, w1g, b1g, hid_o, hid_g);
    k24_conv2_up<<<dim3(H0, 2, B_N), 256, 0, stream>>>(
        x, hid_o, hid_g, w2o, b2o, w2g, b2g, beta, v_out, y_out, gup);
}

// Round 2
// 152.326 us; speedup vs baseline: 1.8143x; 1.8143x over previous
//
#include <hip/hip_runtime.h>
#include <math.h>

// Problem constants
#define B_N   4
#define CIN   21
#define HIDC  48
#define H0    81
#define NP    6561      // 81*81
#define HH    324
#define NPH   104976    // 324*324

__device__ __forceinline__ float tanh_fast(float x) {
    float e = __expf(2.f * x);
    return 1.f - 2.f / (e + 1.f);
}

// ---------------------------------------------------------------------------
// K1 v6: conv1 both heads (21 -> 96 = 48 o + 48 g), relu. MLP-first layout:
// block = 256 consecutive pixels, blockIdx.y = 12-oc group (8 groups of 12).
// x reads straight from L1/L2 (fully coalesced, no LDS staging, no barrier
// in the hot path, no bank conflicts); weights 9.1 KB in LDS, read as
// wave-uniform float4 broadcasts. 832 blocks, FMA-bound (~6 us floor).
// ---------------------------------------------------------------------------
__global__ __launch_bounds__(256) void k1_conv1(
    const float* __restrict__ x,
    const float* __restrict__ w1o, const float* __restrict__ b1o,
    const float* __restrict__ w1g, const float* __restrict__ b1g,
    float* __restrict__ hid_o, float* __restrict__ hid_g)
{
    __shared__ __align__(16) float wt[189 * 12];  // [ict*12 + oc]
    __shared__ float bs[12];
    const int tid = threadIdx.x;
    const int grp = blockIdx.y;          // 0..7 ; 0..3 -> head_o, 4..7 -> head_g
    const int b   = blockIdx.z;
    const bool head_o = (grp < 4);
    const int ocb = (grp & 3) * 12;      // oc base within the head
    const float* wsrc = head_o ? w1o : w1g;
    for (int i = tid; i < 189 * 12; i += 256) {
        const int ict = i / 12, oc = i - ict * 12;
        wt[i] = wsrc[(ocb + oc) * 189 + ict];
    }
    if (tid < 12) bs[tid] = (head_o ? b1o : b1g)[ocb + tid];
    __syncthreads();

    const int px = blockIdx.x * 256 + tid;
    const bool valid = (px < NP);
    const int oy = px / H0, ox = px - oy * H0;
    const float* xb = x + (size_t)b * CIN * NP;

    float acc[12];
    #pragma unroll
    for (int j = 0; j < 12; j++) acc[j] = bs[j];

    for (int ic = 0; ic < CIN; ic++) {
        const float* xc = xb + ic * NP;
        float xv[9];
        #pragma unroll
        for (int ky = 0; ky < 3; ky++) {
            const int iy = oy + ky - 1;
            const bool rok = valid && ((unsigned)iy < (unsigned)H0);
            #pragma unroll
            for (int kx = 0; kx < 3; kx++) {
                const int ix = ox + kx - 1;
                const bool ok = rok && ((unsigned)ix < (unsigned)H0);
                xv[ky * 3 + kx] = ok ? xc[iy * H0 + ix] : 0.f;
            }
        }
        #pragma unroll
        for (int tap = 0; tap < 9; tap++) {
            const float4 w0 = *(const float4*)&wt[(ic * 9 + tap) * 12];
            const float4 w1 = *(const float4*)&wt[(ic * 9 + tap) * 12 + 4];
            const float4 w2 = *(const float4*)&wt[(ic * 9 + tap) * 12 + 8];
            const float wj[12] = {w0.x, w0.y, w0.z, w0.w, w1.x, w1.y, w1.z, w1.w,
                                  w2.x, w2.y, w2.z, w2.w};
            const float xvt = xv[tap];
            #pragma unroll
            for (int j = 0; j < 12; j++) acc[j] = fmaf(xvt, wj[j], acc[j]);
        }
    }

    if (valid) {
        float* outp = (head_o ? hid_o : hid_g) + ((size_t)b * HIDC + ocb) * NP + px;
        #pragma unroll
        for (int j = 0; j < 12; j++) outp[j * NP] = fmaxf(acc[j], 0.f);
    }
}

// ---------------------------------------------------------------------------
// K2 v4 (unchanged): conv2 both heads + mask epilogue, MLP-first design.
// ---------------------------------------------------------------------------
__global__ __launch_bounds__(256) void k2_conv2_masks(
    const float* __restrict__ hid_o, const float* __restrict__ hid_g,
    const float* __restrict__ w2o, const float* __restrict__ b2o,
    const float* __restrict__ w2g, const float* __restrict__ b2g,
    float* __restrict__ v_out,
    float* __restrict__ g_buf, float* __restrict__ m_lp, float* __restrict__ m_hp)
{
    __shared__ __align__(16) float wo_s[HIDC * 9 * 8];  // [(ic*9+tap)*8 + d]
    __shared__ float wg_s[HIDC * 9];
    __shared__ float red[4][32][12];
    __shared__ float res_s[32][28];
    const int tid = threadIdx.x;
    const int b = blockIdx.y;

    for (int i = tid; i < HIDC * 9 * 8; i += 256) {
        const int d = i / (HIDC * 9), r = i - d * (HIDC * 9);
        wo_s[r * 8 + d] = w2o[i];
    }
    for (int i = tid; i < HIDC * 9; i += 256) wg_s[i] = w2g[i];
    __syncthreads();

    const int pxl = tid & 31;
    const int s   = tid >> 5;                // 0..7
    const int w   = tid >> 6;                // wave
    const int px  = blockIdx.x * 32 + pxl;
    const bool valid = (px < NP);
    const int oy = px / H0, ox = px - oy * H0;
    const int ic0 = s * 6;
    const float* po = hid_o + ((size_t)b * HIDC + ic0) * NP;
    const float* pg = hid_g + ((size_t)b * HIDC + ic0) * NP;

    float a[8] = {0.f, 0.f, 0.f, 0.f, 0.f, 0.f, 0.f, 0.f};
    float ag = 0.f;

    #pragma unroll 1
    for (int ky = 0; ky < 3; ky++) {
        const int iy = oy + ky - 1;
        const bool rok = valid && ((unsigned)iy < (unsigned)H0);
        #pragma unroll
        for (int kx = 0; kx < 3; kx++) {
            const int ix = ox + kx - 1;
            const bool ok = rok && ((unsigned)ix < (unsigned)H0);
            const int off = iy * H0 + ix;
            const int tap = ky * 3 + kx;
            #pragma unroll
            for (int j = 0; j < 6; j++) {
                const float vo = ok ? po[j * NP + off] : 0.f;
                const float vg = ok ? pg[j * NP + off] : 0.f;
                const int wb = ((ic0 + j) * 9 + tap) * 8;
                const float4 wA = *(const float4*)&wo_s[wb];
                const float4 wB = *(const float4*)&wo_s[wb + 4];
                a[0] = fmaf(vo, wA.x, a[0]); a[1] = fmaf(vo, wA.y, a[1]);
                a[2] = fmaf(vo, wA.z, a[2]); a[3] = fmaf(vo, wA.w, a[3]);
                a[4] = fmaf(vo, wB.x, a[4]); a[5] = fmaf(vo, wB.y, a[5]);
                a[6] = fmaf(vo, wB.z, a[6]); a[7] = fmaf(vo, wB.w, a[7]);
                ag = fmaf(vg, wg_s[(ic0 + j) * 9 + tap], ag);
            }
        }
    }

    #pragma unroll
    for (int n = 0; n < 8; n++) a[n] += __shfl_xor(a[n], 32);
    ag += __shfl_xor(ag, 32);
    if ((tid & 32) == 0) {
        #pragma unroll
        for (int n = 0; n < 8; n++) red[w][pxl][n] = a[n];
        red[w][pxl][8] = ag;
    }
    __syncthreads();

    if (tid < 32 && valid) {
        float v[8];
        #pragma unroll
        for (int n = 0; n < 8; n++)
            v[n] = tanh_fast(red[0][tid][n] + red[1][tid][n] + red[2][tid][n]
                             + red[3][tid][n] + b2o[n]);
        const float agf = red[0][tid][8] + red[1][tid][8] + red[2][tid][8]
                        + red[3][tid][8] + b2g[0];
        const float g = 1.f / (1.f + __expf(-agf));

        constexpr float DT[8][9] = {
            {-1, 0, 1, -1, 0, 1, -1, 0, 1},
            {-1,-1, 0, -1, 0, 1,  0, 1, 1},
            {-1,-1,-1,  0, 0, 0,  1, 1, 1},
            { 0,-1,-1,  1, 0,-1,  1, 1, 0},
            { 1, 0,-1,  1, 0,-1,  1, 0,-1},
            { 1, 1, 0,  1, 0,-1,  0,-1,-1},
            { 1, 1, 1,  0, 0, 0, -1,-1,-1},
            { 0, 1, 1, -1, 0, 1, -1,-1, 0}};
        float ker[9];
        #pragma unroll
        for (int n = 0; n < 9; n++) {
            float t = 0.f;
            #pragma unroll
            for (int d = 0; d < 8; d++) t += v[d] * DT[d][n];
            ker[n] = -0.125f * t;
        }
        ker[4] += 2.5f;
        float mx = ker[0];
        #pragma unroll
        for (int n = 1; n < 9; n++) mx = fmaxf(mx, ker[n]);
        float exn[9], sum = 0.f;
        #pragma unroll
        for (int n = 0; n < 9; n++) { exn[n] = __expf((ker[n] - mx) * 2.0f); sum += exn[n]; }
        const float rs = 1.f / sum;
        float mean = 0.f;
        #pragma unroll
        for (int n = 0; n < 9; n++) mean += ker[n];
        mean *= (1.f / 9.f);
        float den = 1e-8f;
        #pragma unroll
        for (int n = 0; n < 9; n++) den += fabsf(ker[n] - mean);
        const float rd = 1.f / den;

        #pragma unroll
        for (int n = 0; n < 8; n++) res_s[tid][n] = v[n];
        res_s[tid][8] = g;
        #pragma unroll
        for (int n = 0; n < 9; n++) {
            res_s[tid][9 + n]  = exn[n] * rs;
            res_s[tid][18 + n] = (ker[n] - mean) * rd;
        }
    }
    __syncthreads();

    const int px0 = blockIdx.x * 32;
    for (int j = tid; j < 27 * 32; j += 256) {
        const int plane = j >> 5, pl = j & 31;
        const int p = px0 + pl;
        if (p >= NP) continue;
        const float val = res_s[pl][plane];
        float* dst;
        if (plane < 8)        dst = v_out + ((size_t)b * 8 + plane) * NP;
        else if (plane == 8)  dst = g_buf + (size_t)b * NP;
        else if (plane < 18)  dst = m_lp + ((size_t)b * 9 + (plane - 9)) * NP;
        else                  dst = m_hp + ((size_t)b * 9 + (plane - 18)) * NP;
        dst[p] = val;
    }
}

// ---------------------------------------------------------------------------
// K4 v3: hi-res blend, low-res-row-centric. Block = (low-res row h0r, half
// of the channel planes, b). Stage masks/g (6 KB) + 3 x-rows (11 KB) ONCE,
// phase A computes per-(c,wq) aggregates into LDS, phase B emits 4 hi-res
// rows x 11 planes (float4/thread, coalesced). Kills the 22x mask re-fetch
// of the previous per-channel grid (~250 MB -> ~15 MB of cache traffic).
// ---------------------------------------------------------------------------
__global__ __launch_bounds__(256) void k4_up(
    const float* __restrict__ x, const float* __restrict__ g_buf,
    const float* __restrict__ m_lp, const float* __restrict__ m_hp,
    const float* __restrict__ beta,
    float* __restrict__ y_out, float* __restrict__ gup_out)
{
    __shared__ float ml_s[9][81];
    __shared__ float mh_s[9][81];
    __shared__ float g_s[81];
    __shared__ float xrow[3][11][84];
    __shared__ float alp_s[11][84];
    __shared__ float ahp_s[11][84];
    const int tid  = threadIdx.x;
    const int h0r  = blockIdx.x;         // 0..80
    const int ygrp = blockIdx.y;         // 0..1
    const int b    = blockIdx.z;
    const int c0   = ygrp * 11;          // channels c0..c0+nc-1
    const int nc   = (ygrp == 0) ? 11 : 10;

    // stage masks + gate for this low-res row
    const int rb = h0r * H0;
    for (int i = tid; i < 19 * 81; i += 256) {
        const int pl = i / 81, wq = i - pl * 81;
        if (pl < 9)       ml_s[pl][wq] = m_lp[((size_t)b * 9 + pl) * NP + rb + wq];
        else if (pl < 18) mh_s[pl - 9][wq] = m_hp[((size_t)b * 9 + (pl - 9)) * NP + rb + wq];
        else              g_s[wq] = g_buf[(size_t)b * NP + rb + wq];
    }
    // stage the 3 (reflected) x rows for my channels
    const int r0 = (h0r == 0) ? 1 : h0r - 1;
    const int r2 = (h0r == H0 - 1) ? H0 - 2 : h0r + 1;
    const int rr[3] = {r0, h0r, r2};
    for (int i = tid; i < 3 * nc * 81; i += 256) {
        const int t = i / (nc * 81), rem = i - t * nc * 81;
        const int cc = rem / 81, wq = rem - cc * 81;
        xrow[t][cc][wq] = x[((size_t)b * CIN + c0 + cc) * NP + rr[t] * H0 + wq];
    }
    __syncthreads();

    // phase A: per-(c,wq) low-res aggregates
    for (int i = tid; i < nc * 81; i += 256) {
        const int cc = i / 81, wq = i - cc * 81;
        const int xm = (wq == 0) ? 1 : wq - 1;
        const int xp = (wq == H0 - 1) ? H0 - 2 : wq + 1;
        float alp = 0.f, ahp = 0.f;
        #pragma unroll
        for (int t = 0; t < 3; t++) {
            const float p0 = xrow[t][cc][xm];
            const float p1 = xrow[t][cc][wq];
            const float p2 = xrow[t][cc][xp];
            alp += p0 * ml_s[t * 3 + 0][wq] + p1 * ml_s[t * 3 + 1][wq] + p2 * ml_s[t * 3 + 2][wq];
            ahp += p0 * mh_s[t * 3 + 0][wq] + p1 * mh_s[t * 3 + 1][wq] + p2 * mh_s[t * 3 + 2][wq];
        }
        alp_s[cc][wq] = alp;
        ahp_s[cc][wq] = ahp;
    }
    __syncthreads();

    const float tb = tanh_fast(beta[0]);
    // phase B: 11 planes x 4 hi-res rows x 81 float4s
    for (int i = tid; i < 11 * 4 * 81; i += 256) {
        const int pl = i / 324, rem = i - pl * 324;
        const int dh = rem / 81, wq = rem - dh * 81;
        const int H = h0r * 4 + dh;
        if (ygrp == 1 && pl == 10) {
            const float g = g_s[wq];
            *reinterpret_cast<float4*>(gup_out + (size_t)b * NPH + H * HH + wq * 4) =
                make_float4(g, g, g, g);
            continue;
        }
        const int cc = pl;
        const int c = c0 + pl;
        const float g = g_s[wq];
        const float lam = 0.15f * (1.f - g);
        const float gh = tb * g;
        const float alp = alp_s[cc][wq];
        const float ahp = ahp_s[cc][wq];
        // bilinear from staged rows
        const float ysf = (float)H * (80.f / 323.f);
        int y0 = (int)ysf;
        if (y0 > H0 - 2) y0 = H0 - 2;
        const float wy = ysf - (float)y0;
        const int sy = y0 - h0r + 1;    // 0 or 1 (proved in range)
        const int xm = (wq == 0) ? 1 : wq - 1;   // staged col for wq-1 (never used when wq==0)
        const int xp = (wq == H0 - 1) ? H0 - 2 : wq + 1;  // never used when wq==80
        const float a0 = xrow[sy][cc][(wq == 0) ? 0 : xm];
        const float a1 = xrow[sy][cc][wq];
        const float a2 = xrow[sy][cc][(wq == H0 - 1) ? H0 - 1 : xp];
        const float b0 = xrow[sy + 1][cc][(wq == 0) ? 0 : xm];
        const float b1 = xrow[sy + 1][cc][wq];
        const float b2 = xrow[sy + 1][cc][(wq == H0 - 1) ? H0 - 1 : xp];
        float res[4];
        #pragma unroll
        for (int k = 0; k < 4; k++) {
            const int W = wq * 4 + k;
            const float xsf = (float)W * (80.f / 323.f);
            int x0 = (int)xsf;
            if (x0 > H0 - 2) x0 = H0 - 2;
            const float wx = xsf - (float)x0;
            const int sx = x0 - wq + 1;   // 0 or 1
            const float top = (sx == 0) ? a0 + (a1 - a0) * wx : a1 + (a2 - a1) * wx;
            const float bot = (sx == 0) ? b0 + (b1 - b0) * wx : b1 + (b2 - b1) * wx;
            const float xup = top + (bot - top) * wy;
            res[k] = xup + lam * (alp - xup) + gh * ahp;
        }
        *reinterpret_cast<float4*>(y_out + ((size_t)b * CIN + c) * NPH + H * HH + wq * 4) =
            make_float4(res[0], res[1], res[2], res[3]);
    }
}

// ---------------------------------------------------------------------------
extern "C" void kernel_launch(void* const* d_in, const int* in_sizes, int n_in,
                              void* d_out, int out_size, void* d_ws, size_t ws_size,
                              hipStream_t stream)
{
    const float* x    = (const float*)d_in[0];
    const float* w1o  = (const float*)d_in[1];
    const float* b1o  = (const float*)d_in[2];
    const float* w2o  = (const float*)d_in[3];
    const float* b2o  = (const float*)d_in[4];
    const float* w1g  = (const float*)d_in[5];
    const float* b1g  = (const float*)d_in[6];
    const float* w2g  = (const float*)d_in[7];
    const float* b2g  = (const float*)d_in[8];
    const float* beta = (const float*)d_in[9];
    float* out = (float*)d_out;
    float* wsf = (float*)d_ws;

    float* hid_o = wsf;
    float* hid_g = hid_o + (size_t)B_N * HIDC * NP;
    float* m_lp  = hid_g + (size_t)B_N * HIDC * NP;
    float* m_hp  = m_lp + (size_t)B_N * 9 * NP;
    float* g_buf = m_hp + (size_t)B_N * 9 * NP;

    // output layout: y [4,21,324,324], v [4,8,81,81], g_up [4,1,324,324]
    float* y_out = out;
    float* v_out = out + (size_t)B_N * CIN * NPH;
    float* gup   = v_out + (size_t)B_N * 8 * NP;

    k1_conv1<<<dim3((NP + 255) / 256, 8, B_N), 256, 0, stream>>>(
        x, w1o, b1o, w1g, b1g, hid_o, hid_g);
    k2_conv2_masks<<<dim3((NP + 31) / 32, B_N), 256, 0, stream>>>(
        hid_o, hid_g, w2o, b2o, w2g, b2g, v_out, g_buf, m_lp, m_hp);
    k4_up<<<dim3(H0, 2, B_N), 256, 0, stream>>>(x, g_buf, m_lp, m_hp, beta, y_out, gup);
}

// Round 3
// 146.150 us; speedup vs baseline: 1.8909x; 1.0423x over previous
//
#include <hip/hip_runtime.h>
#include <math.h>

// Problem constants
#define B_N   4
#define CIN   21
#define HIDC  48
#define H0    81
#define NP    6561      // 81*81
#define HH    324
#define NPH   104976    // 324*324

__device__ __forceinline__ float tanh_fast(float x) {
    float e = __expf(2.f * x);
    return 1.f - 2.f / (e + 1.f);
}

// ---------------------------------------------------------------------------
// K1 v6 (unchanged): conv1 both heads (21 -> 96 = 48 o + 48 g), relu.
// MLP-first layout: block = 256 consecutive pixels, blockIdx.y = 12-oc group.
// ---------------------------------------------------------------------------
__global__ __launch_bounds__(256) void k1_conv1(
    const float* __restrict__ x,
    const float* __restrict__ w1o, const float* __restrict__ b1o,
    const float* __restrict__ w1g, const float* __restrict__ b1g,
    float* __restrict__ hid_o, float* __restrict__ hid_g)
{
    __shared__ __align__(16) float wt[189 * 12];  // [ict*12 + oc]
    __shared__ float bs[12];
    const int tid = threadIdx.x;
    const int grp = blockIdx.y;          // 0..7 ; 0..3 -> head_o, 4..7 -> head_g
    const int b   = blockIdx.z;
    const bool head_o = (grp < 4);
    const int ocb = (grp & 3) * 12;      // oc base within the head
    const float* wsrc = head_o ? w1o : w1g;
    for (int i = tid; i < 189 * 12; i += 256) {
        const int ict = i / 12, oc = i - ict * 12;
        wt[i] = wsrc[(ocb + oc) * 189 + ict];
    }
    if (tid < 12) bs[tid] = (head_o ? b1o : b1g)[ocb + tid];
    __syncthreads();

    const int px = blockIdx.x * 256 + tid;
    const bool valid = (px < NP);
    const int oy = px / H0, ox = px - oy * H0;
    const float* xb = x + (size_t)b * CIN * NP;

    float acc[12];
    #pragma unroll
    for (int j = 0; j < 12; j++) acc[j] = bs[j];

    for (int ic = 0; ic < CIN; ic++) {
        const float* xc = xb + ic * NP;
        float xv[9];
        #pragma unroll
        for (int ky = 0; ky < 3; ky++) {
            const int iy = oy + ky - 1;
            const bool rok = valid && ((unsigned)iy < (unsigned)H0);
            #pragma unroll
            for (int kx = 0; kx < 3; kx++) {
                const int ix = ox + kx - 1;
                const bool ok = rok && ((unsigned)ix < (unsigned)H0);
                xv[ky * 3 + kx] = ok ? xc[iy * H0 + ix] : 0.f;
            }
        }
        #pragma unroll
        for (int tap = 0; tap < 9; tap++) {
            const float4 w0 = *(const float4*)&wt[(ic * 9 + tap) * 12];
            const float4 w1 = *(const float4*)&wt[(ic * 9 + tap) * 12 + 4];
            const float4 w2 = *(const float4*)&wt[(ic * 9 + tap) * 12 + 8];
            const float wj[12] = {w0.x, w0.y, w0.z, w0.w, w1.x, w1.y, w1.z, w1.w,
                                  w2.x, w2.y, w2.z, w2.w};
            const float xvt = xv[tap];
            #pragma unroll
            for (int j = 0; j < 12; j++) acc[j] = fmaf(xvt, wj[j], acc[j]);
        }
    }

    if (valid) {
        float* outp = (head_o ? hid_o : hid_g) + ((size_t)b * HIDC + ocb) * NP + px;
        #pragma unroll
        for (int j = 0; j < 12; j++) outp[j * NP] = fmaxf(acc[j], 0.f);
    }
}

// ---------------------------------------------------------------------------
// K2UP: k2 v4 conv2+masks, with k4's upsample fused on as phases 6a/6b that
// consume the masks straight from LDS (res_s). Pixel-centric (32 px/block,
// 824 blocks) -- keeps k2's proven L2 locality, unlike the failed row-centric
// k24. res_s padded to stride 29 (coprime with 32 banks) -> conflict-free
// per-pixel mask reads. x neighborhood (8.6 KB/block) served from L1.
// Eliminates: k4 launch+drain, mask round-trip through HBM, k4's staging.
// ---------------------------------------------------------------------------
__global__ __launch_bounds__(256) void k2up(
    const float* __restrict__ x,
    const float* __restrict__ hid_o, const float* __restrict__ hid_g,
    const float* __restrict__ w2o, const float* __restrict__ b2o,
    const float* __restrict__ w2g, const float* __restrict__ b2g,
    const float* __restrict__ beta,
    float* __restrict__ v_out, float* __restrict__ y_out,
    float* __restrict__ gup_out)
{
    __shared__ __align__(16) float wo_s[HIDC * 9 * 8];  // [(ic*9+tap)*8 + d]
    __shared__ float wg_s[HIDC * 9];
    __shared__ float red[4][32][12];
    __shared__ float res_s[32][29];     // 29 coprime w/ 32 banks: conflict-free
    __shared__ float alp2[CIN][32];
    __shared__ float ahp2[CIN][32];
    const int tid = threadIdx.x;
    const int b = blockIdx.y;

    for (int i = tid; i < HIDC * 9 * 8; i += 256) {
        const int d = i / (HIDC * 9), r = i - d * (HIDC * 9);
        wo_s[r * 8 + d] = w2o[i];
    }
    for (int i = tid; i < HIDC * 9; i += 256) wg_s[i] = w2g[i];
    __syncthreads();

    const int pxl = tid & 31;
    const int s   = tid >> 5;                // 0..7
    const int w   = tid >> 6;                // wave
    const int px0 = blockIdx.x * 32;
    const int px  = px0 + pxl;
    const bool valid = (px < NP);
    const int oy = px / H0, ox = px - oy * H0;
    const int ic0 = s * 6;
    const float* po = hid_o + ((size_t)b * HIDC + ic0) * NP;
    const float* pg = hid_g + ((size_t)b * HIDC + ic0) * NP;

    float a[8] = {0.f, 0.f, 0.f, 0.f, 0.f, 0.f, 0.f, 0.f};
    float ag = 0.f;

    #pragma unroll 1
    for (int ky = 0; ky < 3; ky++) {
        const int iy = oy + ky - 1;
        const bool rok = valid && ((unsigned)iy < (unsigned)H0);
        #pragma unroll
        for (int kx = 0; kx < 3; kx++) {
            const int ix = ox + kx - 1;
            const bool ok = rok && ((unsigned)ix < (unsigned)H0);
            const int off = iy * H0 + ix;
            const int tap = ky * 3 + kx;
            #pragma unroll
            for (int j = 0; j < 6; j++) {
                const float vo = ok ? po[j * NP + off] : 0.f;
                const float vg = ok ? pg[j * NP + off] : 0.f;
                const int wb = ((ic0 + j) * 9 + tap) * 8;
                const float4 wA = *(const float4*)&wo_s[wb];
                const float4 wB = *(const float4*)&wo_s[wb + 4];
                a[0] = fmaf(vo, wA.x, a[0]); a[1] = fmaf(vo, wA.y, a[1]);
                a[2] = fmaf(vo, wA.z, a[2]); a[3] = fmaf(vo, wA.w, a[3]);
                a[4] = fmaf(vo, wB.x, a[4]); a[5] = fmaf(vo, wB.y, a[5]);
                a[6] = fmaf(vo, wB.z, a[6]); a[7] = fmaf(vo, wB.w, a[7]);
                ag = fmaf(vg, wg_s[(ic0 + j) * 9 + tap], ag);
            }
        }
    }

    #pragma unroll
    for (int n = 0; n < 8; n++) a[n] += __shfl_xor(a[n], 32);
    ag += __shfl_xor(ag, 32);
    if ((tid & 32) == 0) {
        #pragma unroll
        for (int n = 0; n < 8; n++) red[w][pxl][n] = a[n];
        red[w][pxl][8] = ag;
    }
    __syncthreads();

    if (tid < 32 && valid) {
        float v[8];
        #pragma unroll
        for (int n = 0; n < 8; n++)
            v[n] = tanh_fast(red[0][tid][n] + red[1][tid][n] + red[2][tid][n]
                             + red[3][tid][n] + b2o[n]);
        const float agf = red[0][tid][8] + red[1][tid][8] + red[2][tid][8]
                        + red[3][tid][8] + b2g[0];
        const float g = 1.f / (1.f + __expf(-agf));

        constexpr float DT[8][9] = {
            {-1, 0, 1, -1, 0, 1, -1, 0, 1},
            {-1,-1, 0, -1, 0, 1,  0, 1, 1},
            {-1,-1,-1,  0, 0, 0,  1, 1, 1},
            { 0,-1,-1,  1, 0,-1,  1, 1, 0},
            { 1, 0,-1,  1, 0,-1,  1, 0,-1},
            { 1, 1, 0,  1, 0,-1,  0,-1,-1},
            { 1, 1, 1,  0, 0, 0, -1,-1,-1},
            { 0, 1, 1, -1, 0, 1, -1,-1, 0}};
        float ker[9];
        #pragma unroll
        for (int n = 0; n < 9; n++) {
            float t = 0.f;
            #pragma unroll
            for (int d = 0; d < 8; d++) t += v[d] * DT[d][n];
            ker[n] = -0.125f * t;
        }
        ker[4] += 2.5f;
        float mx = ker[0];
        #pragma unroll
        for (int n = 1; n < 9; n++) mx = fmaxf(mx, ker[n]);
        float exn[9], sum = 0.f;
        #pragma unroll
        for (int n = 0; n < 9; n++) { exn[n] = __expf((ker[n] - mx) * 2.0f); sum += exn[n]; }
        const float rs = 1.f / sum;
        float mean = 0.f;
        #pragma unroll
        for (int n = 0; n < 9; n++) mean += ker[n];
        mean *= (1.f / 9.f);
        float den = 1e-8f;
        #pragma unroll
        for (int n = 0; n < 9; n++) den += fabsf(ker[n] - mean);
        const float rd = 1.f / den;

        #pragma unroll
        for (int n = 0; n < 8; n++) res_s[tid][n] = v[n];
        res_s[tid][8] = g;
        #pragma unroll
        for (int n = 0; n < 9; n++) {
            res_s[tid][9 + n]  = exn[n] * rs;
            res_s[tid][18 + n] = (ker[n] - mean) * rd;
        }
    }
    __syncthreads();

    // ---- v scatter (exactly one iteration: 8 planes x 32 px = 256) ------
    {
        const int plane = tid >> 5, pl = tid & 31;
        const int p = px0 + pl;
        if (p < NP) v_out[((size_t)b * 8 + plane) * NP + p] = res_s[pl][plane];
    }

    // ---- phase 6a: per (c,pxl) low-res aggregates (reflect taps) --------
    for (int i = tid; i < CIN * 32; i += 256) {
        const int c = i >> 5, pl = i & 31;
        const int p = px0 + pl;
        if (p >= NP) continue;
        const int py = p / H0, pxc = p - py * H0;
        const int ym = (py == 0) ? 1 : py - 1;
        const int yp = (py == H0 - 1) ? H0 - 2 : py + 1;
        const int xm = (pxc == 0) ? 1 : pxc - 1;
        const int xp = (pxc == H0 - 1) ? H0 - 2 : pxc + 1;
        const float* xc = x + ((size_t)b * CIN + c) * NP;
        const int ry[3] = {ym, py, yp};
        const int rx[3] = {xm, pxc, xp};
        float alp = 0.f, ahp = 0.f;
        #pragma unroll
        for (int t = 0; t < 3; t++) {
            const float* xr = xc + ry[t] * H0;
            #pragma unroll
            for (int u = 0; u < 3; u++) {
                const float xv = xr[rx[u]];
                alp = fmaf(xv, res_s[pl][9 + t * 3 + u], alp);
                ahp = fmaf(xv, res_s[pl][18 + t * 3 + u], ahp);
            }
        }
        alp2[c][pl] = alp;
        ahp2[c][pl] = ahp;
    }
    __syncthreads();

    // ---- phase 6b: emit 22 planes x 4 hi-res rows x 32 float4 -----------
    const float tb = tanh_fast(beta[0]);
    for (int i = tid; i < 22 * 4 * 32; i += 256) {
        const int pl  = i >> 7;          // 0..21
        const int rem = i & 127;
        const int dh  = rem >> 5, pp = rem & 31;
        const int p = px0 + pp;
        if (p >= NP) continue;
        const int py = p / H0, pxc = p - py * H0;
        const int H = py * 4 + dh;
        const float g = res_s[pp][8];
        if (pl == 21) {
            *reinterpret_cast<float4*>(gup_out + (size_t)b * NPH + H * HH + pxc * 4) =
                make_float4(g, g, g, g);
            continue;
        }
        const int c = pl;
        const float lam = 0.15f * (1.f - g);
        const float gh = tb * g;
        const float alp = alp2[c][pp];
        const float ahp = ahp2[c][pp];
        // bilinear (align_corners): rows y0,y0+1 and cols in {pxc-1,pxc,pxc+1}
        const float ysf = (float)H * (80.f / 323.f);
        int y0 = (int)ysf;
        if (y0 > H0 - 2) y0 = H0 - 2;
        const float wy = ysf - (float)y0;
        const float* xc = x + ((size_t)b * CIN + c) * NP;
        const int cm = (pxc == 0) ? 0 : pxc - 1;
        const int cp = (pxc == H0 - 1) ? H0 - 1 : pxc + 1;
        const float a0 = xc[y0 * H0 + cm];
        const float a1 = xc[y0 * H0 + pxc];
        const float a2 = xc[y0 * H0 + cp];
        const float b0 = xc[(y0 + 1) * H0 + cm];
        const float b1 = xc[(y0 + 1) * H0 + pxc];
        const float b2 = xc[(y0 + 1) * H0 + cp];
        float res[4];
        #pragma unroll
        for (int k = 0; k < 4; k++) {
            const int W = pxc * 4 + k;
            const float xsf = (float)W * (80.f / 323.f);
            int x0 = (int)xsf;
            if (x0 > H0 - 2) x0 = H0 - 2;
            const float wx = xsf - (float)x0;
            const int sx = x0 - pxc + 1;  // 0 or 1
            const float top = (sx == 0) ? fmaf(a1 - a0, wx, a0) : fmaf(a2 - a1, wx, a1);
            const float bot = (sx == 0) ? fmaf(b1 - b0, wx, b0) : fmaf(b2 - b1, wx, b1);
            const float xup = fmaf(bot - top, wy, top);
            res[k] = fmaf(lam, alp - xup, xup) + gh * ahp;
        }
        *reinterpret_cast<float4*>(y_out + ((size_t)b * CIN + c) * NPH + H * HH + pxc * 4) =
            make_float4(res[0], res[1], res[2], res[3]);
    }
}

// ---------------------------------------------------------------------------
extern "C" void kernel_launch(void* const* d_in, const int* in_sizes, int n_in,
                              void* d_out, int out_size, void* d_ws, size_t ws_size,
                              hipStream_t stream)
{
    const float* x    = (const float*)d_in[0];
    const float* w1o  = (const float*)d_in[1];
    const float* b1o  = (const float*)d_in[2];
    const float* w2o  = (const float*)d_in[3];
    const float* b2o  = (const float*)d_in[4];
    const float* w1g  = (const float*)d_in[5];
    const float* b1g  = (const float*)d_in[6];
    const float* w2g  = (const float*)d_in[7];
    const float* b2g  = (const float*)d_in[8];
    const float* beta = (const float*)d_in[9];
    float* out = (float*)d_out;
    float* wsf = (float*)d_ws;

    float* hid_o = wsf;
    float* hid_g = hid_o + (size_t)B_N * HIDC * NP;

    // output layout: y [4,21,324,324], v [4,8,81,81], g_up [4,1,324,324]
    float* y_out = out;
    float* v_out = out + (size_t)B_N * CIN * NPH;
    float* gup   = v_out + (size_t)B_N * 8 * NP;

    k1_conv1<<<dim3((NP + 255) / 256, 8, B_N), 256, 0, stream>>>(
        x, w1o, b1o, w1g, b1g, hid_o, hid_g);
    k2up<<<dim3((NP + 31) / 32, B_N), 256, 0, stream>>>(
        x, hid_o, hid_g, w2o, b2o, w2g, b2g, beta, v_out, y_out, gup);
}